// Round 17
// baseline (12817.119 us; speedup 1.0000x reference)
//
#include <hip/hip_runtime.h>
#include <stddef.h>

typedef unsigned int u32;
typedef __attribute__((ext_vector_type(8))) short short8;
typedef __attribute__((ext_vector_type(4))) float f32x4;

#define TC 64        // timestep chunk
#define NCHUNK 8
#define CAPIT 200    // fast-poll attempts before permanent device-scope fallback

__device__ __forceinline__ float sigmoidf_(float x) {
    return 1.0f / (1.0f + __expf(-x));
}
__device__ __forceinline__ float tanhf_(float x) {
    float ax = fabsf(x);
    float e = __expf(-2.0f * ax);
    float t = (1.0f - e) / (1.0f + e);
    return copysignf(t, x);
}
__device__ __forceinline__ u32 cvtpk(float lo, float hi) {
    u32 r;
    asm("v_cvt_pk_bf16_f32 %0, %1, %2" : "=v"(r) : "v"(lo), "v"(hi));
    return r;
}
// stores: fast (XCD-L2 scope, sc0) and safe (device scope, sc0 sc1)
__device__ __forceinline__ void stg_u32_l(u32* p, u32 v) {
    asm volatile("global_store_dword %0, %1, off sc0" :: "v"(p), "v"(v) : "memory");
}
__device__ __forceinline__ void stg_u32_g(u32* p, u32 v) {
    asm volatile("global_store_dword %0, %1, off sc0 sc1" :: "v"(p), "v"(v) : "memory");
}
// poll 16 packed (bf16 h | tag<<16) words = 64 B; pack to 2x int4 of bf16 pairs
#define TAGCHK(q) ok &= (((u32)(q).x >> 16) == tt) & (((u32)(q).y >> 16) == tt) & \
                        (((u32)(q).z >> 16) == tt) & (((u32)(q).w >> 16) == tt)
#define PKW(a, b) (int)(((u32)(a) & 0xffffu) | ((u32)(b) << 16))
__device__ __forceinline__ bool poll16_l(const u32* p, u32 tt, int4& P0, int4& P1) {
    int4 q0, q1, q2, q3;
    asm volatile(
        "global_load_dwordx4 %0, %4, off sc0\n\t"
        "global_load_dwordx4 %1, %4, off offset:16 sc0\n\t"
        "global_load_dwordx4 %2, %4, off offset:32 sc0\n\t"
        "global_load_dwordx4 %3, %4, off offset:48 sc0\n\t"
        "s_waitcnt vmcnt(0)"
        : "=&v"(q0), "=&v"(q1), "=&v"(q2), "=&v"(q3) : "v"(p) : "memory");
    bool ok = true;
    TAGCHK(q0); TAGCHK(q1); TAGCHK(q2); TAGCHK(q3);
    P0.x = PKW(q0.x, q0.y); P0.y = PKW(q0.z, q0.w);
    P0.z = PKW(q1.x, q1.y); P0.w = PKW(q1.z, q1.w);
    P1.x = PKW(q2.x, q2.y); P1.y = PKW(q2.z, q2.w);
    P1.z = PKW(q3.x, q3.y); P1.w = PKW(q3.z, q3.w);
    return ok;
}
__device__ __forceinline__ bool poll16_g(const u32* p, u32 tt, int4& P0, int4& P1) {
    int4 q0, q1, q2, q3;
    asm volatile(
        "global_load_dwordx4 %0, %4, off sc0 sc1\n\t"
        "global_load_dwordx4 %1, %4, off offset:16 sc0 sc1\n\t"
        "global_load_dwordx4 %2, %4, off offset:32 sc0 sc1\n\t"
        "global_load_dwordx4 %3, %4, off offset:48 sc0 sc1\n\t"
        "s_waitcnt vmcnt(0)"
        : "=&v"(q0), "=&v"(q1), "=&v"(q2), "=&v"(q3) : "v"(p) : "memory");
    bool ok = true;
    TAGCHK(q0); TAGCHK(q1); TAGCHK(q2); TAGCHK(q3);
    P0.x = PKW(q0.x, q0.y); P0.y = PKW(q0.z, q0.w);
    P0.z = PKW(q1.x, q1.y); P0.w = PKW(q1.z, q1.w);
    P1.x = PKW(q2.x, q2.y); P1.y = PKW(q2.z, q2.w);
    P1.z = PKW(q3.x, q3.y); P1.w = PKW(q3.z, q3.w);
    return ok;
}

// ============================================================================
// proj2: paired input-projection GEMMs (fp32, proven). tb<0 -> skip.
// ============================================================================
#define APITCH 132
#define BPITCH 132

__global__ void __launch_bounds__(256, 2)
proj2(const float* __restrict__ WA, const float* __restrict__ bihA,
      const float* __restrict__ bhhA, const float* __restrict__ XA,
      size_t sXbA, size_t sXtA, int tbA, float* __restrict__ xWA,
      const float* __restrict__ WB, const float* __restrict__ bihB,
      const float* __restrict__ bhhB, const float* __restrict__ XB,
      size_t sXbB, size_t sXtB, int tbB, float* __restrict__ xWB)
{
    const int half = blockIdx.z;
    const int tb = half ? tbB : tbA;
    if (tb < 0) return;
    const float* W   = half ? WB   : WA;
    const float* bih = half ? bihB : bihA;
    const float* bhh = half ? bhhB : bhhA;
    const float* X   = half ? XB   : XA;
    const size_t sXb = half ? sXbB : sXbA;
    const size_t sXt = half ? sXtB : sXtA;
    float* xW        = half ? xWB  : xWA;

    __shared__ float As[32][APITCH];
    __shared__ float Bs[32][BPITCH];
    const int tid = threadIdx.x;
    const int mbase = blockIdx.x * 128;
    const int nt = blockIdx.y;
    const int tm = tid >> 4;
    const int tn = tid & 15;
    float acc[8][8] = {};

    for (int kc = 0; kc < 512; kc += 32) {
        __syncthreads();
#pragma unroll
        for (int u = 0; u < 4; ++u) {
            const int f = u * 256 + tid;
            const int m = f >> 3, k4 = f & 7;
            const float4 v = *(const float4*)(W + (size_t)(mbase + m) * 512 + kc + k4 * 4);
            As[k4 * 4 + 0][m] = v.x; As[k4 * 4 + 1][m] = v.y;
            As[k4 * 4 + 2][m] = v.z; As[k4 * 4 + 3][m] = v.w;
        }
#pragma unroll
        for (int u = 0; u < 4; ++u) {
            const int f = u * 256 + tid;
            const int n = f >> 3, k4 = f & 7;
            const int tl = n >> 5, b = n & 31;
            const float4 v = *(const float4*)(X + (size_t)b * sXb +
                                              (size_t)(tb + nt * 4 + tl) * sXt + kc + k4 * 4);
            Bs[k4 * 4 + 0][n] = v.x; Bs[k4 * 4 + 1][n] = v.y;
            Bs[k4 * 4 + 2][n] = v.z; Bs[k4 * 4 + 3][n] = v.w;
        }
        __syncthreads();
#pragma unroll 8
        for (int kk = 0; kk < 32; ++kk) {
            const float4 a0 = *(const float4*)&As[kk][tm * 8];
            const float4 a1 = *(const float4*)&As[kk][tm * 8 + 4];
            const float4 b0 = *(const float4*)&Bs[kk][tn * 8];
            const float4 b1 = *(const float4*)&Bs[kk][tn * 8 + 4];
            const float am[8] = {a0.x,a0.y,a0.z,a0.w,a1.x,a1.y,a1.z,a1.w};
            const float bn[8] = {b0.x,b0.y,b0.z,b0.w,b1.x,b1.y,b1.z,b1.w};
#pragma unroll
            for (int i = 0; i < 8; ++i)
#pragma unroll
                for (int j = 0; j < 8; ++j)
                    acc[i][j] = fmaf(am[i], bn[j], acc[i][j]);
        }
    }
    const int tl_loc = nt * 4 + (tn >> 2);
    const int bcol = (tn & 3) * 8;
#pragma unroll
    for (int i = 0; i < 8; ++i) {
        const int m = mbase + tm * 8 + i;
        const float bias = bih[m] + bhh[m];
        float* dst = xW + ((size_t)tl_loc * 2048 + m) * 32 + bcol;
        float4 v0 = {acc[i][0] + bias, acc[i][1] + bias, acc[i][2] + bias, acc[i][3] + bias};
        float4 v1 = {acc[i][4] + bias, acc[i][5] + bias, acc[i][6] + bias, acc[i][7] + bias};
        *(float4*)dst = v0;
        *(float4*)(dst + 4) = v1;
    }
}

// ============================================================================
// lstm_recx: MFMA recurrence with XCD-local fast sync.
//   Grid 256 x 512. Role by xcd = bid&7: xcd==0 -> layer A (32 blocks, all on
//   XCD0 if HW round-robins bid%8 -> XCD, so the whole sync domain shares one
//   L2); xcd==1 -> layer B on XCD1; others exit.
//   Ring payload: one u32 per h = (bf16(h) | (t+1)<<16) -- tag travels with
//   data, 4B. Fast ring = sc0 (XCD-L2 scope); safe ring = sc0 sc1 mirrors
//   every publish. Consumer tries fast CAPIT times ONCE; on failure flips to
//   the safe ring permanently (correct even if the XCD mapping assumption is
//   wrong -- then this degrades to proven R8 semantics).
//   No producer-side vmcnt/barrier for publishes (tags are self-validating).
//   MFMA engine identical to R15 (verified absmax 0.00195).
// ============================================================================
__global__ void __launch_bounds__(512, 1)
lstm_recx(const float* __restrict__ WhhA, const float* __restrict__ xWA,
          float* __restrict__ hbufA, size_t sTA, size_t sBA, int tsubA,
          float* __restrict__ cstA, u32* __restrict__ ringFA,
          u32* __restrict__ ringSA, int t0A,
          const float* __restrict__ WhhB, const float* __restrict__ xWB,
          float* __restrict__ hbufB, size_t sTB, size_t sBB, int tsubB,
          float* __restrict__ cstB, u32* __restrict__ ringFB,
          u32* __restrict__ ringSB, int t0B)
{
    const int bid = blockIdx.x;
    const int xcd = bid & 7;
    if (xcd > 1) return;
    const int half = xcd;
    const int t0 = half ? t0B : t0A;
    if (t0 < 0) return;
    const float* Whh = half ? WhhB : WhhA;
    const float* xW  = half ? xWB  : xWA;
    float* hbuf      = half ? hbufB : hbufA;
    const size_t sT  = half ? sTB : sTA;
    const size_t sB  = half ? sBB : sBA;
    const int tsub   = half ? tsubB : tsubA;
    float* cst       = half ? cstB : cstA;
    u32* ringF       = half ? ringFB : ringFA;  // [4][32][512] u32
    u32* ringS       = half ? ringSB : ringSA;

    __shared__ int4 xh4[32 * 64];               // bf16 h(t-1), 32 KB

    const int tid = threadIdx.x;
    const int lb = bid >> 3;                    // 0..31 row-block of this layer
    const int hb = lb << 4;
    const int w = tid >> 6, l = tid & 63;
    const int ct = w >> 2, h4 = w & 3;
    const int q = l >> 4, cl = l & 15;

    // ---- A-fragments: W_hh gate-interleaved rows, bf16, resident (64 VGPR) ----
    const int g_a = cl & 3, hp_a = cl >> 2;
    const int jw = (g_a << 9) + hb + (h4 << 2) + hp_a;
    short8 af[16];
#pragma unroll
    for (int c = 0; c < 16; ++c) {
        const float* wp = Whh + (size_t)jw * 512 + c * 32 + q * 8;
        const float4 v0 = *(const float4*)wp;
        const float4 v1 = *(const float4*)(wp + 4);
        union { short8 s; u32 wd[4]; } u;
        u.wd[0] = cvtpk(v0.x, v0.y); u.wd[1] = cvtpk(v0.z, v0.w);
        u.wd[2] = cvtpk(v1.x, v1.y); u.wd[3] = cvtpk(v1.z, v1.w);
        af[c] = u.s;
    }
    const int hh = hb + (h4 << 2) + q;          // this lane's cell (hidden)
    const int b  = (ct << 4) + cl;              // this lane's cell (batch)
    float c_reg = cst[(size_t)b * 512 + hh];
    const int sn = tid >> 4;                    // staging batch row
    const int sk = (tid & 15) << 5;             // staging hidden base (32 wide)
    const int sb4 = (tid & 15) << 2;            // xh4 slot base
    bool fast_ok = true;

    for (int tl = 0; tl < TC; ++tl) {
        const int t = t0 + tl;
        // xW prefetch: issue early, folded after MFMA (off critical path)
        const float* xwb = xW + ((size_t)tl * 2048 + hh) * 32 + b;
        const float xw0 = xwb[0];
        const float xw1 = xwb[512 * 32];
        const float xw2 = xwb[1024 * 32];
        const float xw3 = xwb[1536 * 32];

        if (t > 0) {
            const u32 tt = (u32)t;
            const size_t rbase = (size_t)((t - 1) & 3) * 16384 + (size_t)sn * 512 + sk;
            int4 p0, p1, p2, p3;
            // half 0 (hidden sk..sk+15)
            bool ok = false;
            if (fast_ok) {
                for (int it = 0; it < CAPIT && !ok; ++it)
                    ok = poll16_l(ringF + rbase, tt, p0, p1);
                if (!ok) fast_ok = false;
            }
            if (!ok) { do { ok = poll16_g(ringS + rbase, tt, p0, p1); } while (!ok); }
            // half 1 (hidden sk+16..sk+31)
            ok = false;
            if (fast_ok) {
                for (int it = 0; it < CAPIT && !ok; ++it)
                    ok = poll16_l(ringF + rbase + 16, tt, p2, p3);
                if (!ok) fast_ok = false;
            }
            if (!ok) { do { ok = poll16_g(ringS + rbase + 16, tt, p2, p3); } while (!ok); }
            xh4[sn * 64 + ((sb4 + 0) ^ (sn & 7))] = p0;
            xh4[sn * 64 + ((sb4 + 1) ^ (sn & 7))] = p1;
            xh4[sn * 64 + ((sb4 + 2) ^ (sn & 7))] = p2;
            xh4[sn * 64 + ((sb4 + 3) ^ (sn & 7))] = p3;
        }
        __syncthreads();                         // xh ready

        f32x4 acc = {0.f, 0.f, 0.f, 0.f};
        if (t > 0) {
#pragma unroll
            for (int c = 0; c < 16; ++c) {
                const int sp = ((c << 2) + q) ^ (b & 7);
                const short8 bf = *reinterpret_cast<const short8*>(&xh4[b * 64 + sp]);
                acc = __builtin_amdgcn_mfma_f32_16x16x32_bf16(af[c], bf, acc, 0, 0, 0);
            }
        }
        // lane-local cell update; xW folded here (prefetched above)
        const float i_ = sigmoidf_(acc[0] + xw0);
        const float f_ = sigmoidf_(acc[1] + xw1);
        const float g_ = tanhf_(acc[2] + xw2);
        const float o_ = sigmoidf_(acc[3] + xw3);
        c_reg = f_ * c_reg + i_ * g_;
        const float hv = o_ * tanhf_(c_reg);
        hbuf[(size_t)(t - tsub) * sT + (size_t)b * sB + hh] = hv;   // plain (next dispatch)
        const u32 pv = (cvtpk(hv, hv) & 0xffffu) | ((u32)(t + 1) << 16);
        u32* rp = (u32*)((size_t)(t & 3) * 16384 + (size_t)b * 512 + hh);
        stg_u32_l(ringF + (size_t)(t & 3) * 16384 + (size_t)b * 512 + hh, pv);
        stg_u32_g(ringS + (size_t)(t & 3) * 16384 + (size_t)b * 512 + hh, pv);
        (void)rp;
        __syncthreads();                         // xh4 consumers done before next stage
    }
    cst[(size_t)b * 512 + hh] = c_reg;
}

// ============================================================================
extern "C" void kernel_launch(void* const* d_in, const int* in_sizes, int n_in,
                              void* d_out, int out_size, void* d_ws, size_t ws_size,
                              hipStream_t stream) {
    const float* inp  = (const float*)d_in[0];
    const float* Wih0 = (const float*)d_in[1];
    const float* Whh0 = (const float*)d_in[2];
    const float* bih0 = (const float*)d_in[3];
    const float* bhh0 = (const float*)d_in[4];
    const float* Wih1 = (const float*)d_in[5];
    const float* Whh1 = (const float*)d_in[6];
    const float* bih1 = (const float*)d_in[7];
    const float* bhh1 = (const float*)d_in[8];
    float* out = (float*)d_out;

    char* ws = (char*)d_ws;
    const size_t CHf = (size_t)TC * 32 * 512;               // floats per h0 chunk slot
    float* h0ring = (float*)ws;                             // 2 x 4 MB
    float* xW0    = (float*)(ws + 8388608);                 // 16 MB
    float* xW1    = (float*)(ws + 25165824);                // 16 MB
    float* cst0   = (float*)(ws + 41943040);                // 64 KB
    float* cst1   = cst0 + 32 * 512;                        // 64 KB
    u32*   ringF0 = (u32*)(ws + 42074112);                  // 256 KB
    u32*   ringF1 = (u32*)(ws + 42336256);                  // 256 KB
    u32*   ringS0 = (u32*)(ws + 42598400);                  // 256 KB
    u32*   ringS1 = (u32*)(ws + 42860544);                  // 256 KB
    // zero c-state + all rings (tag epoch reset) each launch -> replay-safe
    (void)hipMemsetAsync(ws + 41943040, 0, 131072 + 4 * 262144, stream);

    const dim3 gg(16, 16, 2), gb(256);
    const dim3 rg(256), rb(512);
    const size_t sb_in = (size_t)512 * 512;
    const size_t sT_h0 = (size_t)32 * 512;

    // beat k: proj { A = g0(k), B = g1(k-1) }  then  rec { A = r0(k), B = r1(k-1) }
    for (int k = 0; k <= NCHUNK; ++k) {
        const bool hasA = (k < NCHUNK);
        const bool hasB = (k >= 1);
        float* h0A    = h0ring + (size_t)(k & 1) * CHf;
        float* h0Bsrc = h0ring + (size_t)((k - 1) & 1) * CHf;
        hipLaunchKernelGGL(proj2, gg, gb, 0, stream,
                           Wih0, bih0, bhh0, inp, sb_in, (size_t)512,
                           hasA ? k * TC : -1, xW0,
                           Wih1, bih1, bhh1, h0Bsrc, (size_t)512, sT_h0,
                           hasB ? 0 : -1, xW1);
        hipLaunchKernelGGL(lstm_recx, rg, rb, 0, stream,
                           Whh0, xW0, h0A, sT_h0, (size_t)512, k * TC,
                           cst0, ringF0, ringS0, hasA ? k * TC : -1,
                           Whh1, xW1, out, (size_t)512, sb_in, 0,
                           cst1, ringF1, ringS1, hasB ? (k - 1) * TC : -1);
    }
}

// Round 18
// 3663.727 us; speedup vs baseline: 3.4984x; 3.4984x over previous
//
#include <hip/hip_runtime.h>
#include <stddef.h>

typedef unsigned int u32;
typedef __attribute__((ext_vector_type(8))) short short8;
typedef __attribute__((ext_vector_type(4))) float f32x4;

#define TC 64        // timestep chunk
#define NCHUNK 8

__device__ __forceinline__ float sigmoidf_(float x) {
    return 1.0f / (1.0f + __expf(-x));
}
__device__ __forceinline__ float tanhf_(float x) {
    float ax = fabsf(x);
    float e = __expf(-2.0f * ax);
    float t = (1.0f - e) / (1.0f + e);
    return copysignf(t, x);
}
__device__ __forceinline__ u32 cvtpk(float lo, float hi) {
    u32 r;
    asm("v_cvt_pk_bf16_f32 %0, %1, %2" : "=v"(r) : "v"(lo), "v"(hi));
    return r;
}
__device__ __forceinline__ void stg_cu32(u32* p, u32 v) {
    asm volatile("global_store_dword %0, %1, off sc0 sc1" :: "v"(p), "v"(v) : "memory");
}
// tagged poll: 32 packed (bf16h | tag<<16) u32 = 128B, ONE waitcnt (1 RT/retry).
// On success pack 32 bf16 into 4 int4 LDS slots (8 bf16 each).
__device__ __forceinline__ bool poll32(const u32* p, u32 tt,
                                       int4& P0, int4& P1, int4& P2, int4& P3) {
    int4 q0, q1, q2, q3, q4, q5, q6, q7;
    asm volatile(
        "global_load_dwordx4 %0, %8, off sc0 sc1\n\t"
        "global_load_dwordx4 %1, %8, off offset:16 sc0 sc1\n\t"
        "global_load_dwordx4 %2, %8, off offset:32 sc0 sc1\n\t"
        "global_load_dwordx4 %3, %8, off offset:48 sc0 sc1\n\t"
        "global_load_dwordx4 %4, %8, off offset:64 sc0 sc1\n\t"
        "global_load_dwordx4 %5, %8, off offset:80 sc0 sc1\n\t"
        "global_load_dwordx4 %6, %8, off offset:96 sc0 sc1\n\t"
        "global_load_dwordx4 %7, %8, off offset:112 sc0 sc1\n\t"
        "s_waitcnt vmcnt(0)"
        : "=&v"(q0), "=&v"(q1), "=&v"(q2), "=&v"(q3),
          "=&v"(q4), "=&v"(q5), "=&v"(q6), "=&v"(q7)
        : "v"(p) : "memory");
    bool ok = true;
#define TCHK(q) ok &= (((u32)(q).x >> 16) == tt) & (((u32)(q).y >> 16) == tt) & \
                      (((u32)(q).z >> 16) == tt) & (((u32)(q).w >> 16) == tt)
    TCHK(q0); TCHK(q1); TCHK(q2); TCHK(q3); TCHK(q4); TCHK(q5); TCHK(q6); TCHK(q7);
#undef TCHK
#define PKW(a, b) (int)(((u32)(a) & 0xffffu) | ((u32)(b) << 16))
    P0.x = PKW(q0.x, q0.y); P0.y = PKW(q0.z, q0.w);
    P0.z = PKW(q1.x, q1.y); P0.w = PKW(q1.z, q1.w);
    P1.x = PKW(q2.x, q2.y); P1.y = PKW(q2.z, q2.w);
    P1.z = PKW(q3.x, q3.y); P1.w = PKW(q3.z, q3.w);
    P2.x = PKW(q4.x, q4.y); P2.y = PKW(q4.z, q4.w);
    P2.z = PKW(q5.x, q5.y); P2.w = PKW(q5.z, q5.w);
    P3.x = PKW(q6.x, q6.y); P3.y = PKW(q6.z, q6.w);
    P3.z = PKW(q7.x, q7.y); P3.w = PKW(q7.z, q7.w);
#undef PKW
    return ok;
}

// ============================================================================
// proj2: paired input-projection GEMMs (fp32, proven). tb<0 -> skip.
// ============================================================================
#define APITCH 132
#define BPITCH 132

__global__ void __launch_bounds__(256, 2)
proj2(const float* __restrict__ WA, const float* __restrict__ bihA,
      const float* __restrict__ bhhA, const float* __restrict__ XA,
      size_t sXbA, size_t sXtA, int tbA, float* __restrict__ xWA,
      const float* __restrict__ WB, const float* __restrict__ bihB,
      const float* __restrict__ bhhB, const float* __restrict__ XB,
      size_t sXbB, size_t sXtB, int tbB, float* __restrict__ xWB)
{
    const int half = blockIdx.z;
    const int tb = half ? tbB : tbA;
    if (tb < 0) return;
    const float* W   = half ? WB   : WA;
    const float* bih = half ? bihB : bihA;
    const float* bhh = half ? bhhB : bhhA;
    const float* X   = half ? XB   : XA;
    const size_t sXb = half ? sXbB : sXbA;
    const size_t sXt = half ? sXtB : sXtA;
    float* xW        = half ? xWB  : xWA;

    __shared__ float As[32][APITCH];
    __shared__ float Bs[32][BPITCH];
    const int tid = threadIdx.x;
    const int mbase = blockIdx.x * 128;
    const int nt = blockIdx.y;
    const int tm = tid >> 4;
    const int tn = tid & 15;
    float acc[8][8] = {};

    for (int kc = 0; kc < 512; kc += 32) {
        __syncthreads();
#pragma unroll
        for (int u = 0; u < 4; ++u) {
            const int f = u * 256 + tid;
            const int m = f >> 3, k4 = f & 7;
            const float4 v = *(const float4*)(W + (size_t)(mbase + m) * 512 + kc + k4 * 4);
            As[k4 * 4 + 0][m] = v.x; As[k4 * 4 + 1][m] = v.y;
            As[k4 * 4 + 2][m] = v.z; As[k4 * 4 + 3][m] = v.w;
        }
#pragma unroll
        for (int u = 0; u < 4; ++u) {
            const int f = u * 256 + tid;
            const int n = f >> 3, k4 = f & 7;
            const int tl = n >> 5, b = n & 31;
            const float4 v = *(const float4*)(X + (size_t)b * sXb +
                                              (size_t)(tb + nt * 4 + tl) * sXt + kc + k4 * 4);
            Bs[k4 * 4 + 0][n] = v.x; Bs[k4 * 4 + 1][n] = v.y;
            Bs[k4 * 4 + 2][n] = v.z; Bs[k4 * 4 + 3][n] = v.w;
        }
        __syncthreads();
#pragma unroll 8
        for (int kk = 0; kk < 32; ++kk) {
            const float4 a0 = *(const float4*)&As[kk][tm * 8];
            const float4 a1 = *(const float4*)&As[kk][tm * 8 + 4];
            const float4 b0 = *(const float4*)&Bs[kk][tn * 8];
            const float4 b1 = *(const float4*)&Bs[kk][tn * 8 + 4];
            const float am[8] = {a0.x,a0.y,a0.z,a0.w,a1.x,a1.y,a1.z,a1.w};
            const float bn[8] = {b0.x,b0.y,b0.z,b0.w,b1.x,b1.y,b1.z,b1.w};
#pragma unroll
            for (int i = 0; i < 8; ++i)
#pragma unroll
                for (int j = 0; j < 8; ++j)
                    acc[i][j] = fmaf(am[i], bn[j], acc[i][j]);
        }
    }
    const int tl_loc = nt * 4 + (tn >> 2);
    const int bcol = (tn & 3) * 8;
#pragma unroll
    for (int i = 0; i < 8; ++i) {
        const int m = mbase + tm * 8 + i;
        const float bias = bih[m] + bhh[m];
        float* dst = xW + ((size_t)tl_loc * 2048 + m) * 32 + bcol;
        float4 v0 = {acc[i][0] + bias, acc[i][1] + bias, acc[i][2] + bias, acc[i][3] + bias};
        float4 v1 = {acc[i][4] + bias, acc[i][5] + bias, acc[i][6] + bias, acc[i][7] + bias};
        *(float4*)dst = v0;
        *(float4*)(dst + 4) = v1;
    }
}

// ============================================================================
// lstm_recm: MFMA recurrence (R15 engine) + single-RT tagged ring.
//   64 blocks x 512 threads (32/layer, disjoint CUs). Block = 16 hidden x 32
//   batches; wave = one 16x16 MFMA D-tile; gate-interleaved rows make the cell
//   update lane-local. W_hh bf16 A-frags resident (64 VGPR); K=512 via 16
//   MFMAs, no reduction.
//   Ring payload: u32 = bf16(h) | (t+1)<<16 -- tag travels with data. Producer:
//   ONE sc0sc1 4B store, no ack, no prog. Consumer: 128B poll, one waitcnt.
// ============================================================================
__global__ void __launch_bounds__(512, 1)
lstm_recm(const float* __restrict__ WhhA, const float* __restrict__ xWA,
          float* __restrict__ hbufA, size_t sTA, size_t sBA, int tsubA,
          float* __restrict__ cstA, u32* __restrict__ ringA, int t0A,
          const float* __restrict__ WhhB, const float* __restrict__ xWB,
          float* __restrict__ hbufB, size_t sTB, size_t sBB, int tsubB,
          float* __restrict__ cstB, u32* __restrict__ ringB, int t0B)
{
    const int bid = blockIdx.x;
    const int half = bid >> 5;
    const int t0 = half ? t0B : t0A;
    if (t0 < 0) return;
    const float* Whh = half ? WhhB : WhhA;
    const float* xW  = half ? xWB  : xWA;
    float* hbuf      = half ? hbufB : hbufA;
    const size_t sT  = half ? sTB : sTA;
    const size_t sB  = half ? sBB : sBA;
    const int tsub   = half ? tsubB : tsubA;
    float* cst       = half ? cstB : cstA;
    u32* ring        = half ? ringB : ringA;    // [4][32][512] u32

    __shared__ int4 xh4[32 * 64];               // bf16 h(t-1), 32 KB

    const int tid = threadIdx.x;
    const int lb = bid & 31;
    const int hb = lb << 4;                     // hidden slice [hb, hb+16)
    const int w = tid >> 6, l = tid & 63;
    const int ct = w >> 2, h4 = w & 3;
    const int q = l >> 4, cl = l & 15;

    // ---- A-fragments: W_hh gate-interleaved rows, bf16, resident (64 VGPR) ----
    const int g_a = cl & 3, hp_a = cl >> 2;
    const int jw = (g_a << 9) + hb + (h4 << 2) + hp_a;
    short8 af[16];
#pragma unroll
    for (int c = 0; c < 16; ++c) {
        const float* wp = Whh + (size_t)jw * 512 + c * 32 + q * 8;
        const float4 v0 = *(const float4*)wp;
        const float4 v1 = *(const float4*)(wp + 4);
        union { short8 s; u32 wd[4]; } u;
        u.wd[0] = cvtpk(v0.x, v0.y); u.wd[1] = cvtpk(v0.z, v0.w);
        u.wd[2] = cvtpk(v1.x, v1.y); u.wd[3] = cvtpk(v1.z, v1.w);
        af[c] = u.s;
    }
    const int hh = hb + (h4 << 2) + q;          // this lane's cell (hidden)
    const int b  = (ct << 4) + cl;              // this lane's cell (batch)
    float c_reg = cst[(size_t)b * 512 + hh];
    const int sn = tid >> 4;                    // staging batch row
    const int sk = (tid & 15) << 5;             // staging hidden base (32 wide)
    const int sb4 = (tid & 15) << 2;            // xh4 slot base

    for (int tl = 0; tl < TC; ++tl) {
        const int t = t0 + tl;
        // xW prefetch: independent cached loads, folded after MFMA
        const float* xwb = xW + ((size_t)tl * 2048 + hh) * 32 + b;
        const float xw0 = xwb[0];
        const float xw1 = xwb[512 * 32];
        const float xw2 = xwb[1024 * 32];
        const float xw3 = xwb[1536 * 32];

        if (t > 0) {
            const u32* rp = ring + (size_t)((t - 1) & 3) * 16384 + (size_t)sn * 512 + sk;
            int4 p0, p1, p2, p3;
            while (!poll32(rp, (u32)t, p0, p1, p2, p3)) {}
            xh4[sn * 64 + ((sb4 + 0) ^ (sn & 7))] = p0;
            xh4[sn * 64 + ((sb4 + 1) ^ (sn & 7))] = p1;
            xh4[sn * 64 + ((sb4 + 2) ^ (sn & 7))] = p2;
            xh4[sn * 64 + ((sb4 + 3) ^ (sn & 7))] = p3;
        }
        __syncthreads();                         // xh ready

        f32x4 acc = {0.f, 0.f, 0.f, 0.f};
        if (t > 0) {
#pragma unroll
            for (int c = 0; c < 16; ++c) {
                const int sp = ((c << 2) + q) ^ (b & 7);
                const short8 bf = *reinterpret_cast<const short8*>(&xh4[b * 64 + sp]);
                acc = __builtin_amdgcn_mfma_f32_16x16x32_bf16(af[c], bf, acc, 0, 0, 0);
            }
        }
        // lane-local cell update; xW folded here
        const float i_ = sigmoidf_(acc[0] + xw0);
        const float f_ = sigmoidf_(acc[1] + xw1);
        const float g_ = tanhf_(acc[2] + xw2);
        const float o_ = sigmoidf_(acc[3] + xw3);
        c_reg = f_ * c_reg + i_ * g_;
        const float hv = o_ * tanhf_(c_reg);
        hbuf[(size_t)(t - tsub) * sT + (size_t)b * sB + hh] = hv;   // plain (next dispatch)
        const u32 pv = (cvtpk(hv, hv) & 0xffffu) | ((u32)(t + 1) << 16);
        stg_cu32(ring + (size_t)(t & 3) * 16384 + (size_t)b * 512 + hh, pv);
        __syncthreads();                         // xh4 consumers done before next stage
    }
    cst[(size_t)b * 512 + hh] = c_reg;
}

// ============================================================================
extern "C" void kernel_launch(void* const* d_in, const int* in_sizes, int n_in,
                              void* d_out, int out_size, void* d_ws, size_t ws_size,
                              hipStream_t stream) {
    const float* inp  = (const float*)d_in[0];
    const float* Wih0 = (const float*)d_in[1];
    const float* Whh0 = (const float*)d_in[2];
    const float* bih0 = (const float*)d_in[3];
    const float* bhh0 = (const float*)d_in[4];
    const float* Wih1 = (const float*)d_in[5];
    const float* Whh1 = (const float*)d_in[6];
    const float* bih1 = (const float*)d_in[7];
    const float* bhh1 = (const float*)d_in[8];
    float* out = (float*)d_out;

    char* ws = (char*)d_ws;
    const size_t CHf = (size_t)TC * 32 * 512;               // floats per h0 chunk slot
    float* h0ring = (float*)ws;                             // 2 x 4 MB
    float* xW0    = (float*)(ws + 8388608);                 // 16 MB
    float* xW1    = (float*)(ws + 25165824);                // 16 MB
    float* cst0   = (float*)(ws + 41943040);                // 64 KB
    float* cst1   = cst0 + 32 * 512;                        // 64 KB
    u32*   ring0  = (u32*)(ws + 42074112);                  // [4][32][512] u32, 256 KB
    u32*   ring1  = (u32*)(ws + 42336256);                  // 256 KB
    // zero c-state + rings (tag epoch reset) each launch -> replay-safe
    (void)hipMemsetAsync(ws + 41943040, 0, 131072 + 2 * 262144, stream);

    const dim3 gg(16, 16, 2), gb(256);
    const dim3 rg(64), rb(512);
    const size_t sb_in = (size_t)512 * 512;
    const size_t sT_h0 = (size_t)32 * 512;

    // beat k: proj { A = g0(k), B = g1(k-1) }  then  rec { A = r0(k), B = r1(k-1) }
    for (int k = 0; k <= NCHUNK; ++k) {
        const bool hasA = (k < NCHUNK);
        const bool hasB = (k >= 1);
        float* h0A    = h0ring + (size_t)(k & 1) * CHf;
        float* h0Bsrc = h0ring + (size_t)((k - 1) & 1) * CHf;
        hipLaunchKernelGGL(proj2, gg, gb, 0, stream,
                           Wih0, bih0, bhh0, inp, sb_in, (size_t)512,
                           hasA ? k * TC : -1, xW0,
                           Wih1, bih1, bhh1, h0Bsrc, (size_t)512, sT_h0,
                           hasB ? 0 : -1, xW1);
        hipLaunchKernelGGL(lstm_recm, rg, rb, 0, stream,
                           Whh0, xW0, h0A, sT_h0, (size_t)512, k * TC,
                           cst0, ring0, hasA ? k * TC : -1,
                           Whh1, xW1, out, (size_t)512, sb_in, 0,
                           cst1, ring1, hasB ? (k - 1) * TC : -1);
    }
}

// Round 19
// 2943.120 us; speedup vs baseline: 4.3549x; 1.2448x over previous
//
#include <hip/hip_runtime.h>
#include <stddef.h>

typedef unsigned int u32;
typedef __attribute__((ext_vector_type(8))) short short8;
typedef __attribute__((ext_vector_type(4))) float f32x4;

#define TC 64        // timestep chunk
#define NCHUNK 8

__device__ __forceinline__ float sigmoidf_(float x) {
    return 1.0f / (1.0f + __expf(-x));
}
__device__ __forceinline__ float tanhf_(float x) {
    float ax = fabsf(x);
    float e = __expf(-2.0f * ax);
    float t = (1.0f - e) / (1.0f + e);
    return copysignf(t, x);
}
__device__ __forceinline__ u32 cvtpk(float lo, float hi) {
    u32 r;
    asm("v_cvt_pk_bf16_f32 %0, %1, %2" : "=v"(r) : "v"(lo), "v"(hi));
    return r;
}
__device__ __forceinline__ void stg_cu32(u32* p, u32 v) {
    asm volatile("global_store_dword %0, %1, off sc0 sc1" :: "v"(p), "v"(v) : "memory");
}
// tagged poll: 32 packed (bf16h | tag<<16) u32 = 128B, ONE waitcnt (1 RT/retry).
__device__ __forceinline__ bool poll32(const u32* p, u32 tt,
                                       int4& P0, int4& P1, int4& P2, int4& P3) {
    int4 q0, q1, q2, q3, q4, q5, q6, q7;
    asm volatile(
        "global_load_dwordx4 %0, %8, off sc0 sc1\n\t"
        "global_load_dwordx4 %1, %8, off offset:16 sc0 sc1\n\t"
        "global_load_dwordx4 %2, %8, off offset:32 sc0 sc1\n\t"
        "global_load_dwordx4 %3, %8, off offset:48 sc0 sc1\n\t"
        "global_load_dwordx4 %4, %8, off offset:64 sc0 sc1\n\t"
        "global_load_dwordx4 %5, %8, off offset:80 sc0 sc1\n\t"
        "global_load_dwordx4 %6, %8, off offset:96 sc0 sc1\n\t"
        "global_load_dwordx4 %7, %8, off offset:112 sc0 sc1\n\t"
        "s_waitcnt vmcnt(0)"
        : "=&v"(q0), "=&v"(q1), "=&v"(q2), "=&v"(q3),
          "=&v"(q4), "=&v"(q5), "=&v"(q6), "=&v"(q7)
        : "v"(p) : "memory");
    bool ok = true;
#define TCHK(q) ok &= (((u32)(q).x >> 16) == tt) & (((u32)(q).y >> 16) == tt) & \
                      (((u32)(q).z >> 16) == tt) & (((u32)(q).w >> 16) == tt)
    TCHK(q0); TCHK(q1); TCHK(q2); TCHK(q3); TCHK(q4); TCHK(q5); TCHK(q6); TCHK(q7);
#undef TCHK
#define PKW(a, b) (int)(((u32)(a) & 0xffffu) | ((u32)(b) << 16))
    P0.x = PKW(q0.x, q0.y); P0.y = PKW(q0.z, q0.w);
    P0.z = PKW(q1.x, q1.y); P0.w = PKW(q1.z, q1.w);
    P1.x = PKW(q2.x, q2.y); P1.y = PKW(q2.z, q2.w);
    P1.z = PKW(q3.x, q3.y); P1.w = PKW(q3.z, q3.w);
    P2.x = PKW(q4.x, q4.y); P2.y = PKW(q4.z, q4.w);
    P2.z = PKW(q5.x, q5.y); P2.w = PKW(q5.z, q5.w);
    P3.x = PKW(q6.x, q6.y); P3.y = PKW(q6.z, q6.w);
    P3.z = PKW(q7.x, q7.y); P3.w = PKW(q7.z, q7.w);
#undef PKW
    return ok;
}

// ============================================================================
// proj_mfma: paired input-projection GEMMs via bf16 MFMA (fp32 accumulate).
//   M=2048 (gate rows), N=128/block (4 t x 32 b), K=512. 512 thr = 8 waves,
//   each wave = 16 rows x 128 cols (8 D-tiles). LDS bf16 tiles, pitch 20 u32
//   (2-way bank aliasing only). Operand convention = rec engine's (verified):
//   A-lane=row(m), B-lane=col(n), D: col=lane&15, row=(lane>>4)*4+reg.
//   tb < 0 -> half inactive.
// ============================================================================
__global__ void __launch_bounds__(512, 1)
proj_mfma(const float* __restrict__ WA, const float* __restrict__ bihA,
          const float* __restrict__ bhhA, const float* __restrict__ XA,
          size_t sXbA, size_t sXtA, int tbA, float* __restrict__ xWA,
          const float* __restrict__ WB, const float* __restrict__ bihB,
          const float* __restrict__ bhhB, const float* __restrict__ XB,
          size_t sXbB, size_t sXtB, int tbB, float* __restrict__ xWB)
{
    const int half = blockIdx.z;
    const int tb = half ? tbB : tbA;
    if (tb < 0) return;
    const float* W   = half ? WB   : WA;
    const float* bih = half ? bihB : bihA;
    const float* bhh = half ? bhhB : bhhA;
    const float* X   = half ? XB   : XA;
    const size_t sXb = half ? sXbB : sXbA;
    const size_t sXt = half ? sXtB : sXtA;
    float* xW        = half ? xWB  : xWA;

    __shared__ u32 As32[128 * 20];   // 10,240 B bf16 A-tile [row][k32]
    __shared__ u32 Bs32[128 * 20];   // 10,240 B bf16 B-tile [col][k32]

    const int tid = threadIdx.x;
    const int mbase = blockIdx.x * 128;
    const int nt = blockIdx.y;
    const int w = tid >> 6, l = tid & 63;
    const int cl = l & 15, q = l >> 4;
    const int srow = tid >> 2;              // staging row/col 0..127
    const int koff = (tid & 3) * 8;         // staging k-offset (8 fp32)
    const int tl_s = srow >> 5, b_s = srow & 31;

    f32x4 acc[8] = {};                      // 8 col-tiles x 4 f32 = 32 VGPR

    for (int kc = 0; kc < 512; kc += 32) {
        __syncthreads();
        {
            const float* ap = W + (size_t)(mbase + srow) * 512 + kc + koff;
            const float4 v0 = *(const float4*)ap;
            const float4 v1 = *(const float4*)(ap + 4);
            u32* d = &As32[srow * 20 + (koff >> 1)];
            d[0] = cvtpk(v0.x, v0.y); d[1] = cvtpk(v0.z, v0.w);
            d[2] = cvtpk(v1.x, v1.y); d[3] = cvtpk(v1.z, v1.w);
            const float* bp = X + (size_t)b_s * sXb +
                              (size_t)(tb + nt * 4 + tl_s) * sXt + kc + koff;
            const float4 u0 = *(const float4*)bp;
            const float4 u1 = *(const float4*)(bp + 4);
            u32* e = &Bs32[srow * 20 + (koff >> 1)];
            e[0] = cvtpk(u0.x, u0.y); e[1] = cvtpk(u0.z, u0.w);
            e[2] = cvtpk(u1.x, u1.y); e[3] = cvtpk(u1.z, u1.w);
        }
        __syncthreads();
        const short8 af = *reinterpret_cast<const short8*>(
            &As32[(w * 16 + cl) * 20 + q * 4]);
#pragma unroll
        for (int j = 0; j < 8; ++j) {
            const short8 bf = *reinterpret_cast<const short8*>(
                &Bs32[(j * 16 + cl) * 20 + q * 4]);
            acc[j] = __builtin_amdgcn_mfma_f32_16x16x32_bf16(af, bf, acc[j], 0, 0, 0);
        }
    }
    // epilogue: lane owns rows m0..m0+3 (fixed), cols j*16+cl
    const int m0 = mbase + w * 16 + q * 4;
    float bias[4];
#pragma unroll
    for (int r = 0; r < 4; ++r) bias[r] = bih[m0 + r] + bhh[m0 + r];
#pragma unroll
    for (int j = 0; j < 8; ++j) {
        const int nl = j * 16 + cl;
        const int tl_loc = nt * 4 + (nl >> 5);
        const int bb = nl & 31;
        float* dst = xW + ((size_t)tl_loc * 2048 + m0) * 32 + bb;
#pragma unroll
        for (int r = 0; r < 4; ++r)
            dst[(size_t)r * 32] = acc[j][r] + bias[r];
    }
}

// ============================================================================
// lstm_recm: MFMA recurrence (R15 engine) + single-RT tagged ring (R18).
//   Micro-fixes: barrier relocated post-MFMA (stage(t+1) WAR is vs MFMA reads);
//   ring publish issued before the plain hbuf store.
// ============================================================================
__global__ void __launch_bounds__(512, 1)
lstm_recm(const float* __restrict__ WhhA, const float* __restrict__ xWA,
          float* __restrict__ hbufA, size_t sTA, size_t sBA, int tsubA,
          float* __restrict__ cstA, u32* __restrict__ ringA, int t0A,
          const float* __restrict__ WhhB, const float* __restrict__ xWB,
          float* __restrict__ hbufB, size_t sTB, size_t sBB, int tsubB,
          float* __restrict__ cstB, u32* __restrict__ ringB, int t0B)
{
    const int bid = blockIdx.x;
    const int half = bid >> 5;
    const int t0 = half ? t0B : t0A;
    if (t0 < 0) return;
    const float* Whh = half ? WhhB : WhhA;
    const float* xW  = half ? xWB  : xWA;
    float* hbuf      = half ? hbufB : hbufA;
    const size_t sT  = half ? sTB : sTA;
    const size_t sB  = half ? sBB : sBA;
    const int tsub   = half ? tsubB : tsubA;
    float* cst       = half ? cstB : cstA;
    u32* ring        = half ? ringB : ringA;    // [4][32][512] u32

    __shared__ int4 xh4[32 * 64];               // bf16 h(t-1), 32 KB

    const int tid = threadIdx.x;
    const int lb = bid & 31;
    const int hb = lb << 4;                     // hidden slice [hb, hb+16)
    const int w = tid >> 6, l = tid & 63;
    const int ct = w >> 2, h4 = w & 3;
    const int q = l >> 4, cl = l & 15;

    // ---- A-fragments: W_hh gate-interleaved rows, bf16, resident (64 VGPR) ----
    const int g_a = cl & 3, hp_a = cl >> 2;
    const int jw = (g_a << 9) + hb + (h4 << 2) + hp_a;
    short8 af[16];
#pragma unroll
    for (int c = 0; c < 16; ++c) {
        const float* wp = Whh + (size_t)jw * 512 + c * 32 + q * 8;
        const float4 v0 = *(const float4*)wp;
        const float4 v1 = *(const float4*)(wp + 4);
        union { short8 s; u32 wd[4]; } u;
        u.wd[0] = cvtpk(v0.x, v0.y); u.wd[1] = cvtpk(v0.z, v0.w);
        u.wd[2] = cvtpk(v1.x, v1.y); u.wd[3] = cvtpk(v1.z, v1.w);
        af[c] = u.s;
    }
    const int hh = hb + (h4 << 2) + q;          // this lane's cell (hidden)
    const int b  = (ct << 4) + cl;              // this lane's cell (batch)
    float c_reg = cst[(size_t)b * 512 + hh];
    const int sn = tid >> 4;                    // staging batch row
    const int sk = (tid & 15) << 5;             // staging hidden base (32 wide)
    const int sb4 = (tid & 15) << 2;            // xh4 slot base

    for (int tl = 0; tl < TC; ++tl) {
        const int t = t0 + tl;
        // xW prefetch: independent cached loads, folded after MFMA
        const float* xwb = xW + ((size_t)tl * 2048 + hh) * 32 + b;
        const float xw0 = xwb[0];
        const float xw1 = xwb[512 * 32];
        const float xw2 = xwb[1024 * 32];
        const float xw3 = xwb[1536 * 32];

        if (t > 0) {
            const u32* rp = ring + (size_t)((t - 1) & 3) * 16384 + (size_t)sn * 512 + sk;
            int4 p0, p1, p2, p3;
            while (!poll32(rp, (u32)t, p0, p1, p2, p3)) {}
            xh4[sn * 64 + ((sb4 + 0) ^ (sn & 7))] = p0;
            xh4[sn * 64 + ((sb4 + 1) ^ (sn & 7))] = p1;
            xh4[sn * 64 + ((sb4 + 2) ^ (sn & 7))] = p2;
            xh4[sn * 64 + ((sb4 + 3) ^ (sn & 7))] = p3;
        }
        __syncthreads();                         // xh ready

        f32x4 acc = {0.f, 0.f, 0.f, 0.f};
        if (t > 0) {
#pragma unroll
            for (int c = 0; c < 16; ++c) {
                const int sp = ((c << 2) + q) ^ (b & 7);
                const short8 bf = *reinterpret_cast<const short8*>(&xh4[b * 64 + sp]);
                acc = __builtin_amdgcn_mfma_f32_16x16x32_bf16(af[c], bf, acc, 0, 0, 0);
            }
        }
        __syncthreads();                         // MFMA reads done -> next stage may write

        // lane-local cell update; xW folded here
        const float i_ = sigmoidf_(acc[0] + xw0);
        const float f_ = sigmoidf_(acc[1] + xw1);
        const float g_ = tanhf_(acc[2] + xw2);
        const float o_ = sigmoidf_(acc[3] + xw3);
        c_reg = f_ * c_reg + i_ * g_;
        const float hv = o_ * tanhf_(c_reg);
        // publish FIRST (critical path), then plain store for next dispatch
        const u32 pv = (cvtpk(hv, hv) & 0xffffu) | ((u32)(t + 1) << 16);
        stg_cu32(ring + (size_t)(t & 3) * 16384 + (size_t)b * 512 + hh, pv);
        hbuf[(size_t)(t - tsub) * sT + (size_t)b * sB + hh] = hv;
    }
    cst[(size_t)b * 512 + hh] = c_reg;
}

// ============================================================================
extern "C" void kernel_launch(void* const* d_in, const int* in_sizes, int n_in,
                              void* d_out, int out_size, void* d_ws, size_t ws_size,
                              hipStream_t stream) {
    const float* inp  = (const float*)d_in[0];
    const float* Wih0 = (const float*)d_in[1];
    const float* Whh0 = (const float*)d_in[2];
    const float* bih0 = (const float*)d_in[3];
    const float* bhh0 = (const float*)d_in[4];
    const float* Wih1 = (const float*)d_in[5];
    const float* Whh1 = (const float*)d_in[6];
    const float* bih1 = (const float*)d_in[7];
    const float* bhh1 = (const float*)d_in[8];
    float* out = (float*)d_out;

    char* ws = (char*)d_ws;
    const size_t CHf = (size_t)TC * 32 * 512;               // floats per h0 chunk slot
    float* h0ring = (float*)ws;                             // 2 x 4 MB
    float* xW0    = (float*)(ws + 8388608);                 // 16 MB
    float* xW1    = (float*)(ws + 25165824);                // 16 MB
    float* cst0   = (float*)(ws + 41943040);                // 64 KB
    float* cst1   = cst0 + 32 * 512;                        // 64 KB
    u32*   ring0  = (u32*)(ws + 42074112);                  // [4][32][512] u32, 256 KB
    u32*   ring1  = (u32*)(ws + 42336256);                  // 256 KB
    // zero c-state + rings (tag epoch reset) each launch -> replay-safe
    (void)hipMemsetAsync(ws + 41943040, 0, 131072 + 2 * 262144, stream);

    const dim3 gg(16, 16, 2), gb(512);
    const dim3 rg(64), rb(512);
    const size_t sb_in = (size_t)512 * 512;
    const size_t sT_h0 = (size_t)32 * 512;

    // beat k: proj { A = g0(k), B = g1(k-1) }  then  rec { A = r0(k), B = r1(k-1) }
    for (int k = 0; k <= NCHUNK; ++k) {
        const bool hasA = (k < NCHUNK);
        const bool hasB = (k >= 1);
        float* h0A    = h0ring + (size_t)(k & 1) * CHf;
        float* h0Bsrc = h0ring + (size_t)((k - 1) & 1) * CHf;
        hipLaunchKernelGGL(proj_mfma, gg, gb, 0, stream,
                           Wih0, bih0, bhh0, inp, sb_in, (size_t)512,
                           hasA ? k * TC : -1, xW0,
                           Wih1, bih1, bhh1, h0Bsrc, (size_t)512, sT_h0,
                           hasB ? 0 : -1, xW1);
        hipLaunchKernelGGL(lstm_recm, rg, rb, 0, stream,
                           Whh0, xW0, h0A, sT_h0, (size_t)512, k * TC,
                           cst0, ring0, hasA ? k * TC : -1,
                           Whh1, xW1, out, (size_t)512, sb_in, 0,
                           cst1, ring1, hasB ? (k - 1) * TC : -1);
    }
}

// Round 20
// 2881.730 us; speedup vs baseline: 4.4477x; 1.0213x over previous
//
#include <hip/hip_runtime.h>
#include <stddef.h>

typedef unsigned int u32;
typedef __attribute__((ext_vector_type(8))) short short8;
typedef __attribute__((ext_vector_type(4))) float f32x4;

#define TC 64        // timestep chunk
#define NCHUNK 8

__device__ __forceinline__ float sigmoidf_(float x) {
    return 1.0f / (1.0f + __expf(-x));
}
__device__ __forceinline__ float tanhf_(float x) {
    float ax = fabsf(x);
    float e = __expf(-2.0f * ax);
    float t = (1.0f - e) / (1.0f + e);
    return copysignf(t, x);
}
__device__ __forceinline__ u32 cvtpk(float lo, float hi) {
    u32 r;
    asm("v_cvt_pk_bf16_f32 %0, %1, %2" : "=v"(r) : "v"(lo), "v"(hi));
    return r;
}
__device__ __forceinline__ void stg_cu32(u32* p, u32 v) {
    asm volatile("global_store_dword %0, %1, off sc0 sc1" :: "v"(p), "v"(v) : "memory");
}
// tagged poll: 32 packed (bf16h | tag<<16) u32 = 128B, ONE waitcnt (1 RT/retry).
__device__ __forceinline__ bool poll32(const u32* p, u32 tt,
                                       int4& P0, int4& P1, int4& P2, int4& P3) {
    int4 q0, q1, q2, q3, q4, q5, q6, q7;
    asm volatile(
        "global_load_dwordx4 %0, %8, off sc0 sc1\n\t"
        "global_load_dwordx4 %1, %8, off offset:16 sc0 sc1\n\t"
        "global_load_dwordx4 %2, %8, off offset:32 sc0 sc1\n\t"
        "global_load_dwordx4 %3, %8, off offset:48 sc0 sc1\n\t"
        "global_load_dwordx4 %4, %8, off offset:64 sc0 sc1\n\t"
        "global_load_dwordx4 %5, %8, off offset:80 sc0 sc1\n\t"
        "global_load_dwordx4 %6, %8, off offset:96 sc0 sc1\n\t"
        "global_load_dwordx4 %7, %8, off offset:112 sc0 sc1\n\t"
        "s_waitcnt vmcnt(0)"
        : "=&v"(q0), "=&v"(q1), "=&v"(q2), "=&v"(q3),
          "=&v"(q4), "=&v"(q5), "=&v"(q6), "=&v"(q7)
        : "v"(p) : "memory");
    bool ok = true;
#define TCHK(q) ok &= (((u32)(q).x >> 16) == tt) & (((u32)(q).y >> 16) == tt) & \
                      (((u32)(q).z >> 16) == tt) & (((u32)(q).w >> 16) == tt)
    TCHK(q0); TCHK(q1); TCHK(q2); TCHK(q3); TCHK(q4); TCHK(q5); TCHK(q6); TCHK(q7);
#undef TCHK
#define PKW(a, b) (int)(((u32)(a) & 0xffffu) | ((u32)(b) << 16))
    P0.x = PKW(q0.x, q0.y); P0.y = PKW(q0.z, q0.w);
    P0.z = PKW(q1.x, q1.y); P0.w = PKW(q1.z, q1.w);
    P1.x = PKW(q2.x, q2.y); P1.y = PKW(q2.z, q2.w);
    P1.z = PKW(q3.x, q3.y); P1.w = PKW(q3.z, q3.w);
    P2.x = PKW(q4.x, q4.y); P2.y = PKW(q4.z, q4.w);
    P2.z = PKW(q5.x, q5.y); P2.w = PKW(q5.z, q5.w);
    P3.x = PKW(q6.x, q6.y); P3.y = PKW(q6.z, q6.w);
    P3.z = PKW(q7.x, q7.y); P3.w = PKW(q7.z, q7.w);
#undef PKW
    return ok;
}

// ============================================================================
// proj_mfma: paired input-projection GEMMs via bf16 MFMA (fp32 accumulate).
//   M=2048 (gate rows), N=128/block (4 t x 32 b), K=512. 512 thr = 8 waves,
//   each wave = 16 rows x 128 cols (8 D-tiles). LDS bf16 tiles, pitch 20 u32.
//   Operand convention = rec engine's (verified). tb < 0 -> half inactive.
// ============================================================================
__global__ void __launch_bounds__(512, 1)
proj_mfma(const float* __restrict__ WA, const float* __restrict__ bihA,
          const float* __restrict__ bhhA, const float* __restrict__ XA,
          size_t sXbA, size_t sXtA, int tbA, float* __restrict__ xWA,
          const float* __restrict__ WB, const float* __restrict__ bihB,
          const float* __restrict__ bhhB, const float* __restrict__ XB,
          size_t sXbB, size_t sXtB, int tbB, float* __restrict__ xWB)
{
    const int half = blockIdx.z;
    const int tb = half ? tbB : tbA;
    if (tb < 0) return;
    const float* W   = half ? WB   : WA;
    const float* bih = half ? bihB : bihA;
    const float* bhh = half ? bhhB : bhhA;
    const float* X   = half ? XB   : XA;
    const size_t sXb = half ? sXbB : sXbA;
    const size_t sXt = half ? sXtB : sXtA;
    float* xW        = half ? xWB  : xWA;

    __shared__ u32 As32[128 * 20];   // 10,240 B bf16 A-tile [row][k32]
    __shared__ u32 Bs32[128 * 20];   // 10,240 B bf16 B-tile [col][k32]

    const int tid = threadIdx.x;
    const int mbase = blockIdx.x * 128;
    const int nt = blockIdx.y;
    const int w = tid >> 6, l = tid & 63;
    const int cl = l & 15, q = l >> 4;
    const int srow = tid >> 2;              // staging row/col 0..127
    const int koff = (tid & 3) * 8;         // staging k-offset (8 fp32)
    const int tl_s = srow >> 5, b_s = srow & 31;

    f32x4 acc[8] = {};                      // 8 col-tiles x 4 f32 = 32 VGPR

    for (int kc = 0; kc < 512; kc += 32) {
        __syncthreads();
        {
            const float* ap = W + (size_t)(mbase + srow) * 512 + kc + koff;
            const float4 v0 = *(const float4*)ap;
            const float4 v1 = *(const float4*)(ap + 4);
            u32* d = &As32[srow * 20 + (koff >> 1)];
            d[0] = cvtpk(v0.x, v0.y); d[1] = cvtpk(v0.z, v0.w);
            d[2] = cvtpk(v1.x, v1.y); d[3] = cvtpk(v1.z, v1.w);
            const float* bp = X + (size_t)b_s * sXb +
                              (size_t)(tb + nt * 4 + tl_s) * sXt + kc + koff;
            const float4 u0 = *(const float4*)bp;
            const float4 u1 = *(const float4*)(bp + 4);
            u32* e = &Bs32[srow * 20 + (koff >> 1)];
            e[0] = cvtpk(u0.x, u0.y); e[1] = cvtpk(u0.z, u0.w);
            e[2] = cvtpk(u1.x, u1.y); e[3] = cvtpk(u1.z, u1.w);
        }
        __syncthreads();
        const short8 af = *reinterpret_cast<const short8*>(
            &As32[(w * 16 + cl) * 20 + q * 4]);
#pragma unroll
        for (int j = 0; j < 8; ++j) {
            const short8 bf = *reinterpret_cast<const short8*>(
                &Bs32[(j * 16 + cl) * 20 + q * 4]);
            acc[j] = __builtin_amdgcn_mfma_f32_16x16x32_bf16(af, bf, acc[j], 0, 0, 0);
        }
    }
    // epilogue: lane owns rows m0..m0+3 (fixed), cols j*16+cl
    const int m0 = mbase + w * 16 + q * 4;
    float bias[4];
#pragma unroll
    for (int r = 0; r < 4; ++r) bias[r] = bih[m0 + r] + bhh[m0 + r];
#pragma unroll
    for (int j = 0; j < 8; ++j) {
        const int nl = j * 16 + cl;
        const int tl_loc = nt * 4 + (nl >> 5);
        const int bb = nl & 31;
        float* dst = xW + ((size_t)tl_loc * 2048 + m0) * 32 + bb;
#pragma unroll
        for (int r = 0; r < 4; ++r)
            dst[(size_t)r * 32] = acc[j][r] + bias[r];
    }
}

// ============================================================================
// lstm_recm: MFMA recurrence -- EXACT R18 body (measured 301 us/dispatch).
//   64 blocks x 512 threads (32/layer, disjoint CUs). Block = 16 hidden x 32
//   batches; wave = one 16x16 MFMA D-tile; gate-interleaved rows -> lane-local
//   cell update. W_hh bf16 A-frags resident; K=512 via 16 MFMAs, no reduction.
//   Ring: u32 = bf16(h) | (t+1)<<16, sc0sc1; publish immediately post-MFMA
//   (NOT gated on a block barrier -- consumer latency is what matters).
// ============================================================================
__global__ void __launch_bounds__(512, 1)
lstm_recm(const float* __restrict__ WhhA, const float* __restrict__ xWA,
          float* __restrict__ hbufA, size_t sTA, size_t sBA, int tsubA,
          float* __restrict__ cstA, u32* __restrict__ ringA, int t0A,
          const float* __restrict__ WhhB, const float* __restrict__ xWB,
          float* __restrict__ hbufB, size_t sTB, size_t sBB, int tsubB,
          float* __restrict__ cstB, u32* __restrict__ ringB, int t0B)
{
    const int bid = blockIdx.x;
    const int half = bid >> 5;
    const int t0 = half ? t0B : t0A;
    if (t0 < 0) return;
    const float* Whh = half ? WhhB : WhhA;
    const float* xW  = half ? xWB  : xWA;
    float* hbuf      = half ? hbufB : hbufA;
    const size_t sT  = half ? sTB : sTA;
    const size_t sB  = half ? sBB : sBA;
    const int tsub   = half ? tsubB : tsubA;
    float* cst       = half ? cstB : cstA;
    u32* ring        = half ? ringB : ringA;    // [4][32][512] u32

    __shared__ int4 xh4[32 * 64];               // bf16 h(t-1), 32 KB

    const int tid = threadIdx.x;
    const int lb = bid & 31;
    const int hb = lb << 4;                     // hidden slice [hb, hb+16)
    const int w = tid >> 6, l = tid & 63;
    const int ct = w >> 2, h4 = w & 3;
    const int q = l >> 4, cl = l & 15;

    // ---- A-fragments: W_hh gate-interleaved rows, bf16, resident (64 VGPR) ----
    const int g_a = cl & 3, hp_a = cl >> 2;
    const int jw = (g_a << 9) + hb + (h4 << 2) + hp_a;
    short8 af[16];
#pragma unroll
    for (int c = 0; c < 16; ++c) {
        const float* wp = Whh + (size_t)jw * 512 + c * 32 + q * 8;
        const float4 v0 = *(const float4*)wp;
        const float4 v1 = *(const float4*)(wp + 4);
        union { short8 s; u32 wd[4]; } u;
        u.wd[0] = cvtpk(v0.x, v0.y); u.wd[1] = cvtpk(v0.z, v0.w);
        u.wd[2] = cvtpk(v1.x, v1.y); u.wd[3] = cvtpk(v1.z, v1.w);
        af[c] = u.s;
    }
    const int hh = hb + (h4 << 2) + q;          // this lane's cell (hidden)
    const int b  = (ct << 4) + cl;              // this lane's cell (batch)
    float c_reg = cst[(size_t)b * 512 + hh];
    const int sn = tid >> 4;                    // staging batch row
    const int sk = (tid & 15) << 5;             // staging hidden base (32 wide)
    const int sb4 = (tid & 15) << 2;            // xh4 slot base

    for (int tl = 0; tl < TC; ++tl) {
        const int t = t0 + tl;
        // xW prefetch: independent cached loads, folded after MFMA
        const float* xwb = xW + ((size_t)tl * 2048 + hh) * 32 + b;
        const float xw0 = xwb[0];
        const float xw1 = xwb[512 * 32];
        const float xw2 = xwb[1024 * 32];
        const float xw3 = xwb[1536 * 32];

        if (t > 0) {
            const u32* rp = ring + (size_t)((t - 1) & 3) * 16384 + (size_t)sn * 512 + sk;
            int4 p0, p1, p2, p3;
            while (!poll32(rp, (u32)t, p0, p1, p2, p3)) {}
            xh4[sn * 64 + ((sb4 + 0) ^ (sn & 7))] = p0;
            xh4[sn * 64 + ((sb4 + 1) ^ (sn & 7))] = p1;
            xh4[sn * 64 + ((sb4 + 2) ^ (sn & 7))] = p2;
            xh4[sn * 64 + ((sb4 + 3) ^ (sn & 7))] = p3;
        }
        __syncthreads();                         // xh ready

        f32x4 acc = {0.f, 0.f, 0.f, 0.f};
        if (t > 0) {
#pragma unroll
            for (int c = 0; c < 16; ++c) {
                const int sp = ((c << 2) + q) ^ (b & 7);
                const short8 bf = *reinterpret_cast<const short8*>(&xh4[b * 64 + sp]);
                acc = __builtin_amdgcn_mfma_f32_16x16x32_bf16(af[c], bf, acc, 0, 0, 0);
            }
        }
        // lane-local cell update; xW folded here
        const float i_ = sigmoidf_(acc[0] + xw0);
        const float f_ = sigmoidf_(acc[1] + xw1);
        const float g_ = tanhf_(acc[2] + xw2);
        const float o_ = sigmoidf_(acc[3] + xw3);
        c_reg = f_ * c_reg + i_ * g_;
        const float hv = o_ * tanhf_(c_reg);
        hbuf[(size_t)(t - tsub) * sT + (size_t)b * sB + hh] = hv;   // plain (next dispatch)
        const u32 pv = (cvtpk(hv, hv) & 0xffffu) | ((u32)(t + 1) << 16);
        stg_cu32(ring + (size_t)(t & 3) * 16384 + (size_t)b * 512 + hh, pv);
        __syncthreads();                         // xh4 consumers done before next stage
    }
    cst[(size_t)b * 512 + hh] = c_reg;
}

// ============================================================================
extern "C" void kernel_launch(void* const* d_in, const int* in_sizes, int n_in,
                              void* d_out, int out_size, void* d_ws, size_t ws_size,
                              hipStream_t stream) {
    const float* inp  = (const float*)d_in[0];
    const float* Wih0 = (const float*)d_in[1];
    const float* Whh0 = (const float*)d_in[2];
    const float* bih0 = (const float*)d_in[3];
    const float* bhh0 = (const float*)d_in[4];
    const float* Wih1 = (const float*)d_in[5];
    const float* Whh1 = (const float*)d_in[6];
    const float* bih1 = (const float*)d_in[7];
    const float* bhh1 = (const float*)d_in[8];
    float* out = (float*)d_out;

    char* ws = (char*)d_ws;
    const size_t CHf = (size_t)TC * 32 * 512;               // floats per h0 chunk slot
    float* h0ring = (float*)ws;                             // 2 x 4 MB
    float* xW0    = (float*)(ws + 8388608);                 // 16 MB
    float* xW1    = (float*)(ws + 25165824);                // 16 MB
    float* cst0   = (float*)(ws + 41943040);                // 64 KB
    float* cst1   = cst0 + 32 * 512;                        // 64 KB
    u32*   ring0  = (u32*)(ws + 42074112);                  // [4][32][512] u32, 256 KB
    u32*   ring1  = (u32*)(ws + 42336256);                  // 256 KB
    // zero c-state + rings (tag epoch reset) each launch -> replay-safe
    (void)hipMemsetAsync(ws + 41943040, 0, 131072 + 2 * 262144, stream);

    const dim3 gg(16, 16, 2), gb(512);
    const dim3 rg(64), rb(512);
    const size_t sb_in = (size_t)512 * 512;
    const size_t sT_h0 = (size_t)32 * 512;

    // beat k: proj { A = g0(k), B = g1(k-1) }  then  rec { A = r0(k), B = r1(k-1) }
    for (int k = 0; k <= NCHUNK; ++k) {
        const bool hasA = (k < NCHUNK);
        const bool hasB = (k >= 1);
        float* h0A    = h0ring + (size_t)(k & 1) * CHf;
        float* h0Bsrc = h0ring + (size_t)((k - 1) & 1) * CHf;
        hipLaunchKernelGGL(proj_mfma, gg, gb, 0, stream,
                           Wih0, bih0, bhh0, inp, sb_in, (size_t)512,
                           hasA ? k * TC : -1, xW0,
                           Wih1, bih1, bhh1, h0Bsrc, (size_t)512, sT_h0,
                           hasB ? 0 : -1, xW1);
        hipLaunchKernelGGL(lstm_recm, rg, rb, 0, stream,
                           Whh0, xW0, h0A, sT_h0, (size_t)512, k * TC,
                           cst0, ring0, hasA ? k * TC : -1,
                           Whh1, xW1, out, (size_t)512, sb_in, 0,
                           cst1, ring1, hasB ? (k - 1) * TC : -1);
    }
}